// Round 2
// baseline (1484.228 us; speedup 1.0000x reference)
//
#include <hip/hip_runtime.h>
#include <hip/hip_fp16.h>

// Problem: B=256, T=512, F=64, H=128  (GRU-D / BRITS-style recurrence)
// d_in: 0 values,1 masks,2 deltas,3 labels,4 is_train,5 W_dh,6 b_dh,7 W_dx,8 b_dx,
//       9 W_hr,10 b_hr,11 W_fr,12 b_fr,13 W_wc,14 b_wc,15 W_ih,16 b_ih,17 W_hh,
//       18 b_hh,19 W_out,20 b_out
// d_out (fp32): [0]=loss, [1..256]=predictions, [257..]=imputations [B,T,F]

#define NBATCH 256
#define NT 512
#define NF 64
#define NH 128

// ---- workspace byte offsets (all 16B aligned) ----
#define WHH_OFF   0u           // [16][512] uint4 packed f16 rows of W_hh
#define WIH_OFF   131072u      // [16][512] uint4 packed f16 rows of W_ih
#define WHR_OFF   262144u      // [16][64]  uint4 packed f16 rows of W_hr
#define WFR_OFF   278528u      // [8][64]   uint4 packed f16 rows of W_fr (diag zeroed)
#define INVMS_OFF 286720u      // f32[512]
#define ISTR_OFF  288768u      // f32[1]
#define GH_OFF    294912u      // f16 [B*T*128] gamma_h
#define AL_OFF    33849344u    // f16 [B*T*64]  alpha
// total ws needed ~50.7 MB

typedef _Float16 half2_t __attribute__((ext_vector_type(2)));

__device__ __forceinline__ unsigned pack2(float a, float b) {
    __half2 h = __floats2half2_rn(a, b);
    return __builtin_bit_cast(unsigned, h);
}

__device__ __forceinline__ float dot2f(unsigned w, unsigned a, float acc) {
#if __has_builtin(__builtin_amdgcn_fdot2)
    return __builtin_amdgcn_fdot2(__builtin_bit_cast(half2_t, w),
                                  __builtin_bit_cast(half2_t, a), acc, false);
#else
    float2 wf = __half22float2(__builtin_bit_cast(__half2, w));
    float2 af = __half22float2(__builtin_bit_cast(__half2, a));
    return acc + wf.x * af.x + wf.y * af.y;
#endif
}

__device__ __forceinline__ float sigm(float x) { return 1.f / (1.f + __expf(-x)); }
__device__ __forceinline__ float tanh_fast(float x) { return 1.f - 2.f / (__expf(2.f * x) + 1.f); }

// Barrier that drains LDS ops only -- global loads/stores stay in flight.
// __syncthreads() would emit s_waitcnt vmcnt(0) before s_barrier, putting the
// per-step global prefetch (LLC/HBM latency) on the critical path every step.
__device__ __forceinline__ void bar_lds() {
    asm volatile("s_waitcnt lgkmcnt(0)\n\ts_barrier" ::: "memory");
}

// ---------------------------------------------------------------------------
// prep_w: pack W_hh / W_ih / W_hr / W_fr(zero-diag) rows into f16x2 uint4 layout
// layout: region of uint4[NCHUNK][ROWS]; u32 flat idx o -> c=o&3, r, chunk.
// chunk cb covers cols 8cb..8cb+7 of the row.
// ---------------------------------------------------------------------------
__global__ __launch_bounds__(256) void prep_w(const float* __restrict__ Whh,
                                              const float* __restrict__ Wih,
                                              const float* __restrict__ Whr,
                                              const float* __restrict__ Wfr,
                                              unsigned* __restrict__ wsu) {
    int o = blockIdx.x * 256 + threadIdx.x;
    float v0, v1;
    if (o < 32768) {                      // W_hh [512][128]
        int c = o & 3, r = (o >> 2) & 511, cb = o >> 11;
        int col = 8 * cb + 2 * c;
        v0 = Whh[r * 128 + col]; v1 = Whh[r * 128 + col + 1];
    } else if (o < 65536) {               // W_ih [512][128]
        int o2 = o - 32768;
        int c = o2 & 3, r = (o2 >> 2) & 511, cb = o2 >> 11;
        int col = 8 * cb + 2 * c;
        v0 = Wih[r * 128 + col]; v1 = Wih[r * 128 + col + 1];
    } else if (o < 69632) {               // W_hr [64][128]
        int o3 = o - 65536;
        int c = o3 & 3, f = (o3 >> 2) & 63, cb = o3 >> 8;
        int col = 8 * cb + 2 * c;
        v0 = Whr[f * 128 + col]; v1 = Whr[f * 128 + col + 1];
    } else if (o < 71680) {               // W_fr [64][64], zero diagonal
        int o4 = o - 69632;
        int c = o4 & 3, f = (o4 >> 2) & 63, cb = o4 >> 8;
        int col = 8 * cb + 2 * c;
        v0 = (col == f) ? 0.f : Wfr[f * 64 + col];
        v1 = (col + 1 == f) ? 0.f : Wfr[f * 64 + col + 1];
    } else {
        return;
    }
    wsu[o] = pack2(v0, v1);
}

// ---------------------------------------------------------------------------
// prep_msum: invms[t] = 1/(sum_b,f masks[b,t,f] + 1e-5); block 512 does
// inv_istr = 1/(sum is_train + 1e-5) and zeroes d_out[0].
// ---------------------------------------------------------------------------
__global__ __launch_bounds__(256) void prep_msum(const float* __restrict__ masks,
                                                 const float* __restrict__ is_train,
                                                 float* __restrict__ invms,
                                                 float* __restrict__ inv_istr,
                                                 float* __restrict__ d_out0) {
    __shared__ float red[256];
    int tid = threadIdx.x;
    int t = blockIdx.x;
    if (t < NT) {
        int f = tid & 63, br = tid >> 6;
        float s = 0.f;
        for (int i = 0; i < 64; i++) {
            int b = br + i * 4;
            s += masks[((size_t)b * NT + t) * NF + f];
        }
        red[tid] = s;
        __syncthreads();
        for (int off = 128; off > 0; off >>= 1) {
            if (tid < off) red[tid] += red[tid + off];
            __syncthreads();
        }
        if (tid == 0) invms[t] = 1.f / (red[0] + 1e-5f);
    } else {
        red[tid] = is_train[tid];
        __syncthreads();
        for (int off = 128; off > 0; off >>= 1) {
            if (tid < off) red[tid] += red[tid + off];
            __syncthreads();
        }
        if (tid == 0) {
            *inv_istr = 1.f / (red[0] + 1e-5f);
            *d_out0 = 0.f;
        }
    }
}

// ---------------------------------------------------------------------------
// ga_kernel: precompute gamma_h[b,t,128] and alpha[b,t,64] (f16), both pure
// input functions. One (b,t) pair per inner iteration, 32 per block.
// ---------------------------------------------------------------------------
__global__ __launch_bounds__(256) void ga_kernel(const float* __restrict__ deltas,
                                                 const float* __restrict__ masks,
                                                 const float* __restrict__ Wdh,
                                                 const float* __restrict__ bdh,
                                                 const float* __restrict__ Wdx,
                                                 const float* __restrict__ bdx,
                                                 const float* __restrict__ Wwc,
                                                 const float* __restrict__ bwc,
                                                 __half* __restrict__ gh_all,
                                                 __half* __restrict__ al_all) {
    __shared__ unsigned wdhpk[32 * 128];   // [k2][j]  f16x2 of W_dh cols (2k2,2k2+1)
    __shared__ unsigned wwcpk[64 * 64];    // [k2][f]
    __shared__ float sbdh[128], sbdx[64], swdx[64], sbwc[64];
    __shared__ float dbuf[64];
    __shared__ __align__(16) unsigned dpk[32], gxpk[32], mpk2[32];
    int tid = threadIdx.x;

    for (int o = tid; o < 4096; o += 256) {    // W_dh [128][64] -> [k2][j]
        int j = o & 127, k2 = o >> 7;
        wdhpk[o] = pack2(Wdh[j * 64 + 2 * k2], Wdh[j * 64 + 2 * k2 + 1]);
    }
    for (int o = tid; o < 4096; o += 256) {    // W_wc [64][128] -> [k2][f]
        int f = o & 63, k2 = o >> 6;
        wwcpk[o] = pack2(Wwc[f * 128 + 2 * k2], Wwc[f * 128 + 2 * k2 + 1]);
    }
    if (tid < 128) sbdh[tid] = bdh[tid];
    if (tid < 64) {
        sbdx[tid] = bdx[tid];
        swdx[tid] = Wdx[tid * 65];             // diagonal of W_dx
        sbwc[tid] = bwc[tid];
    }
    __syncthreads();

    for (int i = 0; i < 32; i++) {
        int p = blockIdx.x * 32 + i;           // p = b*T + t
        if (tid < 32) {
            float2 dv = ((const float2*)(deltas + (size_t)p * NF))[tid];
            dbuf[2 * tid] = dv.x; dbuf[2 * tid + 1] = dv.y;
            dpk[tid] = pack2(dv.x, dv.y);
        } else if (tid < 64) {
            int q = tid - 32;
            float2 mv = ((const float2*)(masks + (size_t)p * NF))[q];
            mpk2[q] = pack2(mv.x, mv.y);
        }
        __syncthreads();
        if (tid < 64) {
            float gx = __expf(-fmaxf(dbuf[tid] * swdx[tid] + sbdx[tid], 0.f));
            float oth = __shfl_xor(gx, 1);
            if (!(tid & 1)) gxpk[tid >> 1] = pack2(gx, oth);
        }
        __syncthreads();
        if (tid < 128) {
            float a0 = sbdh[tid], a1 = 0.f;
            #pragma unroll
            for (int k8 = 0; k8 < 8; k8++) {
                uint4 dp = *(const uint4*)&dpk[4 * k8];
                a0 = dot2f(wdhpk[(4 * k8 + 0) * 128 + tid], dp.x, a0);
                a1 = dot2f(wdhpk[(4 * k8 + 1) * 128 + tid], dp.y, a1);
                a0 = dot2f(wdhpk[(4 * k8 + 2) * 128 + tid], dp.z, a0);
                a1 = dot2f(wdhpk[(4 * k8 + 3) * 128 + tid], dp.w, a1);
            }
            gh_all[(size_t)p * NH + tid] = __float2half(__expf(-fmaxf(a0 + a1, 0.f)));
        } else if (tid < 192) {
            int f = tid - 128;
            float a0 = sbwc[f], a1 = 0.f;
            #pragma unroll
            for (int k8 = 0; k8 < 8; k8++) {
                uint4 gp = *(const uint4*)&gxpk[4 * k8];
                a0 = dot2f(wwcpk[(4 * k8 + 0) * 64 + f], gp.x, a0);
                a1 = dot2f(wwcpk[(4 * k8 + 1) * 64 + f], gp.y, a1);
                a0 = dot2f(wwcpk[(4 * k8 + 2) * 64 + f], gp.z, a0);
                a1 = dot2f(wwcpk[(4 * k8 + 3) * 64 + f], gp.w, a1);
            }
            #pragma unroll
            for (int k8 = 0; k8 < 8; k8++) {
                uint4 mp = *(const uint4*)&mpk2[4 * k8];
                a0 = dot2f(wwcpk[(32 + 4 * k8 + 0) * 64 + f], mp.x, a0);
                a1 = dot2f(wwcpk[(32 + 4 * k8 + 1) * 64 + f], mp.y, a1);
                a0 = dot2f(wwcpk[(32 + 4 * k8 + 2) * 64 + f], mp.z, a0);
                a1 = dot2f(wwcpk[(32 + 4 * k8 + 3) * 64 + f], mp.w, a1);
            }
            al_all[(size_t)p * NF + f] = __float2half(a0 + a1);
        }
        __syncthreads();
    }
}

// ---------------------------------------------------------------------------
// main_kernel: one block per batch element, 512 threads (8 waves).
// 3 lgkmcnt-only barriers per step (bar_lds): global prefetch + imp stores
// stay in flight across barriers; only waited at their use point one full
// step later.
//   P1: all waves compute h@W_hh gate partials (k-quarter per lane) AND an
//       8-way k-split of x_h = h@W_hr.T; commit prefetched inputs.
//   P2: wave 0 runs the serial imputation chain; waves 1-7 compute the m-half
//       gate partials and stage gamma_h(t+1).
//   P3: all threads finish c_c gate partials, butterfly-reduce within 4-lane
//       quads, LSTM pointwise update in-register (c replicated per quad).
// ---------------------------------------------------------------------------
__global__ __launch_bounds__(512, 2) void main_kernel(
    const float* __restrict__ values, const float* __restrict__ masks,
    const float* __restrict__ labels, const float* __restrict__ is_train,
    const float* __restrict__ b_hr, const float* __restrict__ b_fr,
    const float* __restrict__ b_ih, const float* __restrict__ b_hh,
    const float* __restrict__ W_out, const float* __restrict__ b_out,
    const uint4* __restrict__ whh_ws, const uint4* __restrict__ wih_ws,
    const uint4* __restrict__ whr_ws, const uint4* __restrict__ wfr_ws,
    const float* __restrict__ invms, const float* __restrict__ inv_istr,
    const __half* __restrict__ gh_all, const __half* __restrict__ al_all,
    float* __restrict__ d_out) {
    __shared__ uint4 wfr4[8 * 64];             // 8 KB, [k4][f]
    __shared__ float sbhr[64], sbfr[64];
    __shared__ __align__(16) unsigned hpk[64]; // h packed f16x2
    __shared__ float xp[512];                  // x_h k-partials [kg][f]
    __shared__ float mbuf[64], xbuf[64], albuf[64];
    __shared__ __align__(16) unsigned mpk[32], xcpk[32], ccpk[32];
    __shared__ __align__(16) unsigned ghpk[64];// gamma_h(t+1) packed
    __shared__ float hfin[128];
    __shared__ float sinvt;

    const int tid = threadIdx.x;
    const int b = blockIdx.x;
    const int s = tid & 3;          // k-quarter within quad
    const int cq = tid >> 2;        // LSTM cell 0..127
    const int kg = tid >> 6;        // wave id (x_h k-group)
    const int fl = tid & 63;        // lane within wave

    // ---- persistent register weights ----
    // Per thread: all 4 gates (rows g*128+cq) restricted to k-quarter s.
    uint4 whh_q[16];    // h-half:  4 gates x 4 chunks (cols 32s..32s+31)
    uint4 wihc_q[8];    // c_c-half: 4 gates x 2 chunks (cols 16s..16s+15)
    uint4 wihm_q[8];    // m-half:   4 gates x 2 chunks (cols 64+16s..)
    float bg4[4];
    #pragma unroll
    for (int g = 0; g < 4; g++) {
        int r = g * 128 + cq;
        #pragma unroll
        for (int j = 0; j < 4; j++) whh_q[g * 4 + j] = whh_ws[(4 * s + j) * 512 + r];
        #pragma unroll
        for (int j = 0; j < 2; j++) {
            wihc_q[g * 2 + j] = wih_ws[(2 * s + j) * 512 + r];
            wihm_q[g * 2 + j] = wih_ws[(8 + 2 * s + j) * 512 + r];
        }
        bg4[g] = b_ih[r] + b_hh[r];
    }
    // x_h partial weights: W_hr[fl, 16*kg .. 16*kg+15]
    uint4 whr_pa = whr_ws[(2 * kg) * 64 + fl];
    uint4 whr_pb = whr_ws[(2 * kg + 1) * 64 + fl];
    wfr4[tid] = wfr_ws[tid];
    if (tid < 64) { sbhr[tid] = b_hr[tid]; sbfr[tid] = b_fr[tid]; hpk[tid] = 0u; }

    const float* vp = values + (size_t)b * NT * NF;
    const float* mp = masks + (size_t)b * NT * NF;
    const __half* alp = al_all + (size_t)b * NT * NF;
    const unsigned* ghu = (const unsigned*)(gh_all + (size_t)b * NT * NH);
    float* imp = d_out + 257 + (size_t)b * NT * NF;

    float creg = 0.f;               // c state, replicated across each quad
    float lloss = 0.f;
    float hacc4[4] = {0.f, 0.f, 0.f, 0.f};
    float macc4[4] = {0.f, 0.f, 0.f, 0.f};

    // ---- preamble prefetch: t=0 inputs; gamma_h pipeline is 2 deep ----
    float xn = 0.f, aln = 0.f, invtn = 0.f;
    float2 mn = make_float2(0.f, 0.f);
    unsigned ghA = 0u, ghB = 0u;
    if (tid >= 256 && tid < 320) {
        int q = tid - 256;
        xn = vp[q];
        aln = __half2float(alp[q]);
        if (q == 0) invtn = invms[0];
    } else if (tid >= 320 && tid < 352) {
        mn = ((const float2*)mp)[tid - 320];
    } else if (tid >= 352 && tid < 416) {
        int q = tid - 352;
        ghA = ghu[64 + q];           // gamma_h(1): consumed at P3(t=0)
        ghB = ghu[128 + q];          // gamma_h(2)
    }
    __syncthreads();

    for (int t = 0; t < NT; t++) {
        // ===== P1: commit inputs (loaded a full step ago, no vmcnt stall);
        //           issue next loads; h-gate partials + x_h k-partials =====
        if (tid >= 256 && tid < 320) {
            int q = tid - 256;
            xbuf[q] = xn; albuf[q] = aln;
            if (q == 0) sinvt = invtn;
        } else if (tid >= 320 && tid < 352) {
            int q = tid - 320;
            mbuf[2 * q] = mn.x; mbuf[2 * q + 1] = mn.y;
            mpk[q] = pack2(mn.x, mn.y);
        }
        {
            int tn = (t + 1 < NT) ? (t + 1) : (NT - 1);
            if (tid >= 256 && tid < 320) {
                int q = tid - 256;
                xn = vp[tn * NF + q];
                aln = __half2float(alp[tn * NF + q]);
                if (q == 0) invtn = invms[tn];
            } else if (tid >= 320 && tid < 352) {
                mn = ((const float2*)(mp + tn * NF))[tid - 320];
            }
        }
        // h @ W_hh.T partials (4 gates, k-quarter s)
        #pragma unroll
        for (int g = 0; g < 4; g++) {
            float u0 = 0.f, u1 = 0.f;
            #pragma unroll
            for (int j = 0; j < 4; j++) {
                uint4 hq = *(const uint4*)&hpk[16 * s + 4 * j];
                uint4 w = whh_q[g * 4 + j];
                u0 = dot2f(w.x, hq.x, u0); u1 = dot2f(w.y, hq.y, u1);
                u0 = dot2f(w.z, hq.z, u0); u1 = dot2f(w.w, hq.w, u1);
            }
            hacc4[g] = u0 + u1;
        }
        // x_h partial: output fl, k in [16*kg, 16*kg+16)
        {
            uint4 hpa = *(const uint4*)&hpk[8 * kg];
            uint4 hpb = *(const uint4*)&hpk[8 * kg + 4];
            float p0, p1;
            p0 = dot2f(whr_pa.x, hpa.x, 0.f); p1 = dot2f(whr_pa.y, hpa.y, 0.f);
            p0 = dot2f(whr_pa.z, hpa.z, p0);  p1 = dot2f(whr_pa.w, hpa.w, p1);
            p0 = dot2f(whr_pb.x, hpb.x, p0);  p1 = dot2f(whr_pb.y, hpb.y, p1);
            p0 = dot2f(whr_pb.z, hpb.z, p0);  p1 = dot2f(whr_pb.w, hpb.w, p1);
            xp[tid] = p0 + p1;
        }
        bar_lds();                             // ---- Bar A

        // ===== P2: wave 0 serial imputation chain; waves 1-7 m-dots ======
        if (tid < 64) {
            __builtin_amdgcn_s_setprio(1);
            float xh = sbhr[fl];
            #pragma unroll
            for (int g8 = 0; g8 < 8; g8++) xh += xp[g8 * 64 + fl];
            float xv = xbuf[fl], mv = mbuf[fl], av = albuf[fl], it = sinvt;
            float xc = mv * xv + (1.f - mv) * xh;
            float oth = __shfl_xor(xc, 1);
            if (!(fl & 1)) xcpk[fl >> 1] = pack2(xc, oth);
            float b0 = sbfr[fl], b1 = 0.f;
            #pragma unroll
            for (int k4 = 0; k4 < 8; k4++) {
                uint4 w = wfr4[k4 * 64 + fl];
                uint4 xq = *(const uint4*)&xcpk[4 * k4];
                b0 = dot2f(w.x, xq.x, b0); b1 = dot2f(w.y, xq.y, b1);
                b0 = dot2f(w.z, xq.z, b0); b1 = dot2f(w.w, xq.w, b1);
            }
            float zh = b0 + b1;
            float ch = av * zh + (1.f - av) * xh;
            float cc = mv * xv + (1.f - mv) * ch;
            imp[t * NF + fl] = cc;
            lloss += (fabsf(xv - xh) + fabsf(xv - zh) + fabsf(xv - ch)) * mv * it;
            oth = __shfl_xor(cc, 1);
            if (!(fl & 1)) ccpk[fl >> 1] = pack2(cc, oth);
            __builtin_amdgcn_s_setprio(0);
        } else {
            if (tid >= 352 && tid < 416) {     // stage gamma_h(t+1), advance pipe
                int q = tid - 352;
                ghpk[q] = ghA;
                ghA = ghB;
                int tg = (t + 3 < NT) ? (t + 3) : (NT - 1);
                ghB = ghu[(size_t)tg * 64 + q];
            }
            uint4 mq0 = *(const uint4*)&mpk[8 * s];
            uint4 mq1 = *(const uint4*)&mpk[8 * s + 4];
            #pragma unroll
            for (int g = 0; g < 4; g++) {
                uint4 wa = wihm_q[g * 2], wb = wihm_q[g * 2 + 1];
                float u0 = dot2f(wa.x, mq0.x, 0.f), u1 = dot2f(wa.y, mq0.y, 0.f);
                u0 = dot2f(wa.z, mq0.z, u0); u1 = dot2f(wa.w, mq0.w, u1);
                u0 = dot2f(wb.x, mq1.x, u0); u1 = dot2f(wb.y, mq1.y, u1);
                u0 = dot2f(wb.z, mq1.z, u0); u1 = dot2f(wb.w, mq1.w, u1);
                macc4[g] = u0 + u1;
            }
        }
        bar_lds();                             // ---- Bar B

        // ===== P3: c_c dots, quad butterfly reduce, LSTM pointwise =======
        {
            if (tid < 64) {                    // wave 0's deferred m-dots
                uint4 mq0 = *(const uint4*)&mpk[8 * s];
                uint4 mq1 = *(const uint4*)&mpk[8 * s + 4];
                #pragma unroll
                for (int g = 0; g < 4; g++) {
                    uint4 wa = wihm_q[g * 2], wb = wihm_q[g * 2 + 1];
                    float u0 = dot2f(wa.x, mq0.x, 0.f), u1 = dot2f(wa.y, mq0.y, 0.f);
                    u0 = dot2f(wa.z, mq0.z, u0); u1 = dot2f(wa.w, mq0.w, u1);
                    u0 = dot2f(wb.x, mq1.x, u0); u1 = dot2f(wb.y, mq1.y, u1);
                    u0 = dot2f(wb.z, mq1.z, u0); u1 = dot2f(wb.w, mq1.w, u1);
                    macc4[g] = u0 + u1;
                }
            }
            uint4 cq0 = *(const uint4*)&ccpk[8 * s];
            uint4 cq1 = *(const uint4*)&ccpk[8 * s + 4];
            float gate[4];
            #pragma unroll
            for (int g = 0; g < 4; g++) {
                uint4 wa = wihc_q[g * 2], wb = wihc_q[g * 2 + 1];
                float u0 = dot2f(wa.x, cq0.x, 0.f), u1 = dot2f(wa.y, cq0.y, 0.f);
                u0 = dot2f(wa.z, cq0.z, u0); u1 = dot2f(wa.w, cq0.w, u1);
                u0 = dot2f(wb.x, cq1.x, u0); u1 = dot2f(wb.y, cq1.y, u1);
                u0 = dot2f(wb.z, cq1.z, u0); u1 = dot2f(wb.w, cq1.w, u1);
                float v = hacc4[g] + macc4[g] + (u0 + u1);
                v += __shfl_xor(v, 1);         // combine k-quarters
                v += __shfl_xor(v, 2);
                gate[g] = v + bg4[g];
            }
            // pointwise update, replicated across the 4 lanes of the quad
            float cn = sigm(gate[1]) * creg + sigm(gate[0]) * tanh_fast(gate[2]);
            creg = cn;
            float hn = sigm(gate[3]) * tanh_fast(cn);
            float gm = __half2float(((const __half*)ghpk)[cq]);
            float hd = hn * gm;                // pre-decayed h for step t+1
            float oth = __shfl_xor(hd, 4);     // pair with neighboring cell
            if (!(tid & 7)) hpk[tid >> 3] = pack2(hd, oth);
            if (t == NT - 1 && !(tid & 3)) hfin[cq] = hn;
        }
        bar_lds();                             // ---- Bar C (loop top)
    }

    // ---- finale: y_h, prediction, loss contribution ----
    if (tid < 64) {
        float ll = lloss;
        float yp = hfin[tid] * W_out[tid] + hfin[64 + tid] * W_out[64 + tid];
        #pragma unroll
        for (int off = 32; off > 0; off >>= 1) {
            ll += __shfl_down(ll, off);
            yp += __shfl_down(yp, off);
        }
        if (tid == 0) {
            float yh = yp + b_out[0];
            d_out[1 + b] = 1.f / (1.f + expf(-yh));
            float lab = labels[b], istr = is_train[b];
            float maxv = fmaxf(-yh, 0.f);
            float yl = yh - yh * lab + maxv + logf(expf(-maxv) + expf(-yh - maxv));
            atomicAdd(d_out, ll * (1.f / (float)NT) + 0.3f * yl * istr * (*inv_istr));
        }
    }
}

// ---------------------------------------------------------------------------
extern "C" void kernel_launch(void* const* d_in, const int* in_sizes, int n_in,
                              void* d_out, int out_size, void* d_ws, size_t ws_size,
                              hipStream_t stream) {
    const float* values = (const float*)d_in[0];
    const float* masks = (const float*)d_in[1];
    const float* deltas = (const float*)d_in[2];
    const float* labels = (const float*)d_in[3];
    const float* is_train = (const float*)d_in[4];
    const float* W_dh = (const float*)d_in[5];
    const float* b_dh = (const float*)d_in[6];
    const float* W_dx = (const float*)d_in[7];
    const float* b_dx = (const float*)d_in[8];
    const float* W_hr = (const float*)d_in[9];
    const float* b_hr = (const float*)d_in[10];
    const float* W_fr = (const float*)d_in[11];
    const float* b_fr = (const float*)d_in[12];
    const float* W_wc = (const float*)d_in[13];
    const float* b_wc = (const float*)d_in[14];
    const float* W_ih = (const float*)d_in[15];
    const float* b_ih = (const float*)d_in[16];
    const float* W_hh = (const float*)d_in[17];
    const float* b_hh = (const float*)d_in[18];
    const float* W_out = (const float*)d_in[19];
    const float* b_out = (const float*)d_in[20];

    char* ws = (char*)d_ws;
    unsigned* wsu = (unsigned*)d_ws;
    const uint4* whh_ws = (const uint4*)(ws + WHH_OFF);
    const uint4* wih_ws = (const uint4*)(ws + WIH_OFF);
    const uint4* whr_ws = (const uint4*)(ws + WHR_OFF);
    const uint4* wfr_ws = (const uint4*)(ws + WFR_OFF);
    float* invms = (float*)(ws + INVMS_OFF);
    float* inv_istr = (float*)(ws + ISTR_OFF);
    __half* gh_all = (__half*)(ws + GH_OFF);
    __half* al_all = (__half*)(ws + AL_OFF);
    float* out_f = (float*)d_out;

    prep_w<<<280, 256, 0, stream>>>(W_hh, W_ih, W_hr, W_fr, wsu);
    prep_msum<<<513, 256, 0, stream>>>(masks, is_train, invms, inv_istr, out_f);
    ga_kernel<<<4096, 256, 0, stream>>>(deltas, masks, W_dh, b_dh, W_dx, b_dx,
                                        W_wc, b_wc, gh_all, al_all);
    main_kernel<<<NBATCH, 512, 0, stream>>>(values, masks, labels, is_train,
                                            b_hr, b_fr, b_ih, b_hh, W_out, b_out,
                                            whh_ws, wih_ws, whr_ws, wfr_ws,
                                            invms, inv_istr, gh_all, al_all, out_f);
}

// Round 3
// 1288.961 us; speedup vs baseline: 1.1515x; 1.1515x over previous
//
#include <hip/hip_runtime.h>
#include <hip/hip_fp16.h>

// Problem: B=256, T=512, F=64, H=128  (GRU-D / BRITS-style recurrence)
// d_in: 0 values,1 masks,2 deltas,3 labels,4 is_train,5 W_dh,6 b_dh,7 W_dx,8 b_dx,
//       9 W_hr,10 b_hr,11 W_fr,12 b_fr,13 W_wc,14 b_wc,15 W_ih,16 b_ih,17 W_hh,
//       18 b_hh,19 W_out,20 b_out
// d_out (fp32): [0]=loss, [1..256]=predictions, [257..]=imputations [B,T,F]

#define NBATCH 256
#define NT 512
#define NF 64
#define NH 128

// ---- workspace byte offsets (all 16B aligned) ----
#define WHH_OFF   0u           // [16][512] uint4 packed f16 rows of W_hh
#define WIH_OFF   131072u      // [16][512] uint4 packed f16 rows of W_ih
#define WHR_OFF   262144u      // [16][64]  uint4 packed f16 rows of W_hr
#define WFR_OFF   278528u      // [8][64]   uint4 packed f16 rows of W_fr (diag zeroed)
#define INVMS_OFF 286720u      // f32[512]
#define ISTR_OFF  288768u      // f32[1]
#define GH_OFF    294912u      // f16 [B*T*128] gamma_h
#define AL_OFF    33849344u    // f16 [B*T*64]  alpha
// total ws needed ~50.7 MB

typedef _Float16 half2_t __attribute__((ext_vector_type(2)));

__device__ __forceinline__ unsigned pack2(float a, float b) {
    __half2 h = __floats2half2_rn(a, b);
    return __builtin_bit_cast(unsigned, h);
}

__device__ __forceinline__ float dot2f(unsigned w, unsigned a, float acc) {
#if __has_builtin(__builtin_amdgcn_fdot2)
    return __builtin_amdgcn_fdot2(__builtin_bit_cast(half2_t, w),
                                  __builtin_bit_cast(half2_t, a), acc, false);
#else
    float2 wf = __half22float2(__builtin_bit_cast(__half2, w));
    float2 af = __half22float2(__builtin_bit_cast(__half2, a));
    return acc + wf.x * af.x + wf.y * af.y;
#endif
}

__device__ __forceinline__ float sigm(float x) { return 1.f / (1.f + __expf(-x)); }
__device__ __forceinline__ float tanh_fast(float x) { return 1.f - 2.f / (__expf(2.f * x) + 1.f); }

// Intra-quad butterfly adds via DPP quad_perm (register-only, ~4cy vs ~120cy
// for ds_swizzle-based __shfl_xor).
__device__ __forceinline__ float quad_add_x1(float v) {
    int r = __builtin_amdgcn_update_dpp(0, __builtin_bit_cast(int, v),
                                        0xB1 /*[1,0,3,2]*/, 0xF, 0xF, true);
    return v + __builtin_bit_cast(float, r);
}
__device__ __forceinline__ float quad_add_x2(float v) {
    int r = __builtin_amdgcn_update_dpp(0, __builtin_bit_cast(int, v),
                                        0x4E /*[2,3,0,1]*/, 0xF, 0xF, true);
    return v + __builtin_bit_cast(float, r);
}

// Keep-alive anchor: forces the value to live in a VGPR and makes it opaque,
// so the compiler cannot rematerialize it by re-loading from global memory.
#define KEEP4(u) asm volatile("" : "+v"(u.x), "+v"(u.y), "+v"(u.z), "+v"(u.w))

// ---------------------------------------------------------------------------
// prep_w: pack W_hh / W_ih / W_hr / W_fr(zero-diag) rows into f16x2 uint4 layout
// ---------------------------------------------------------------------------
__global__ __launch_bounds__(256) void prep_w(const float* __restrict__ Whh,
                                              const float* __restrict__ Wih,
                                              const float* __restrict__ Whr,
                                              const float* __restrict__ Wfr,
                                              unsigned* __restrict__ wsu) {
    int o = blockIdx.x * 256 + threadIdx.x;
    float v0, v1;
    if (o < 32768) {                      // W_hh [512][128]
        int c = o & 3, r = (o >> 2) & 511, cb = o >> 11;
        int col = 8 * cb + 2 * c;
        v0 = Whh[r * 128 + col]; v1 = Whh[r * 128 + col + 1];
    } else if (o < 65536) {               // W_ih [512][128]
        int o2 = o - 32768;
        int c = o2 & 3, r = (o2 >> 2) & 511, cb = o2 >> 11;
        int col = 8 * cb + 2 * c;
        v0 = Wih[r * 128 + col]; v1 = Wih[r * 128 + col + 1];
    } else if (o < 69632) {               // W_hr [64][128]
        int o3 = o - 65536;
        int c = o3 & 3, f = (o3 >> 2) & 63, cb = o3 >> 8;
        int col = 8 * cb + 2 * c;
        v0 = Whr[f * 128 + col]; v1 = Whr[f * 128 + col + 1];
    } else if (o < 71680) {               // W_fr [64][64], zero diagonal
        int o4 = o - 69632;
        int c = o4 & 3, f = (o4 >> 2) & 63, cb = o4 >> 8;
        int col = 8 * cb + 2 * c;
        v0 = (col == f) ? 0.f : Wfr[f * 64 + col];
        v1 = (col + 1 == f) ? 0.f : Wfr[f * 64 + col + 1];
    } else {
        return;
    }
    wsu[o] = pack2(v0, v1);
}

// ---------------------------------------------------------------------------
// prep_msum: invms[t] = 1/(sum_b,f masks[b,t,f] + 1e-5); block 512 does
// inv_istr = 1/(sum is_train + 1e-5) and zeroes d_out[0].
// ---------------------------------------------------------------------------
__global__ __launch_bounds__(256) void prep_msum(const float* __restrict__ masks,
                                                 const float* __restrict__ is_train,
                                                 float* __restrict__ invms,
                                                 float* __restrict__ inv_istr,
                                                 float* __restrict__ d_out0) {
    __shared__ float red[256];
    int tid = threadIdx.x;
    int t = blockIdx.x;
    if (t < NT) {
        int f = tid & 63, br = tid >> 6;
        float s = 0.f;
        for (int i = 0; i < 64; i++) {
            int b = br + i * 4;
            s += masks[((size_t)b * NT + t) * NF + f];
        }
        red[tid] = s;
        __syncthreads();
        for (int off = 128; off > 0; off >>= 1) {
            if (tid < off) red[tid] += red[tid + off];
            __syncthreads();
        }
        if (tid == 0) invms[t] = 1.f / (red[0] + 1e-5f);
    } else {
        red[tid] = is_train[tid];
        __syncthreads();
        for (int off = 128; off > 0; off >>= 1) {
            if (tid < off) red[tid] += red[tid + off];
            __syncthreads();
        }
        if (tid == 0) {
            *inv_istr = 1.f / (red[0] + 1e-5f);
            *d_out0 = 0.f;
        }
    }
}

// ---------------------------------------------------------------------------
// ga_kernel: precompute gamma_h[b,t,128] and alpha[b,t,64] (f16), both pure
// input functions. One (b,t) pair per inner iteration, 32 per block.
// ---------------------------------------------------------------------------
__global__ __launch_bounds__(256) void ga_kernel(const float* __restrict__ deltas,
                                                 const float* __restrict__ masks,
                                                 const float* __restrict__ Wdh,
                                                 const float* __restrict__ bdh,
                                                 const float* __restrict__ Wdx,
                                                 const float* __restrict__ bdx,
                                                 const float* __restrict__ Wwc,
                                                 const float* __restrict__ bwc,
                                                 __half* __restrict__ gh_all,
                                                 __half* __restrict__ al_all) {
    __shared__ unsigned wdhpk[32 * 128];   // [k2][j]  f16x2 of W_dh cols (2k2,2k2+1)
    __shared__ unsigned wwcpk[64 * 64];    // [k2][f]
    __shared__ float sbdh[128], sbdx[64], swdx[64], sbwc[64];
    __shared__ float dbuf[64];
    __shared__ __align__(16) unsigned dpk[32], gxpk[32], mpk2[32];
    int tid = threadIdx.x;

    for (int o = tid; o < 4096; o += 256) {    // W_dh [128][64] -> [k2][j]
        int j = o & 127, k2 = o >> 7;
        wdhpk[o] = pack2(Wdh[j * 64 + 2 * k2], Wdh[j * 64 + 2 * k2 + 1]);
    }
    for (int o = tid; o < 4096; o += 256) {    // W_wc [64][128] -> [k2][f]
        int f = o & 63, k2 = o >> 6;
        wwcpk[o] = pack2(Wwc[f * 128 + 2 * k2], Wwc[f * 128 + 2 * k2 + 1]);
    }
    if (tid < 128) sbdh[tid] = bdh[tid];
    if (tid < 64) {
        sbdx[tid] = bdx[tid];
        swdx[tid] = Wdx[tid * 65];             // diagonal of W_dx
        sbwc[tid] = bwc[tid];
    }
    __syncthreads();

    for (int i = 0; i < 32; i++) {
        int p = blockIdx.x * 32 + i;           // p = b*T + t
        if (tid < 32) {
            float2 dv = ((const float2*)(deltas + (size_t)p * NF))[tid];
            dbuf[2 * tid] = dv.x; dbuf[2 * tid + 1] = dv.y;
            dpk[tid] = pack2(dv.x, dv.y);
        } else if (tid < 64) {
            int q = tid - 32;
            float2 mv = ((const float2*)(masks + (size_t)p * NF))[q];
            mpk2[q] = pack2(mv.x, mv.y);
        }
        __syncthreads();
        if (tid < 64) {
            float gx = __expf(-fmaxf(dbuf[tid] * swdx[tid] + sbdx[tid], 0.f));
            float oth = __shfl_xor(gx, 1);
            if (!(tid & 1)) gxpk[tid >> 1] = pack2(gx, oth);
        }
        __syncthreads();
        if (tid < 128) {
            float a0 = sbdh[tid], a1 = 0.f;
            #pragma unroll
            for (int k8 = 0; k8 < 8; k8++) {
                uint4 dp = *(const uint4*)&dpk[4 * k8];
                a0 = dot2f(wdhpk[(4 * k8 + 0) * 128 + tid], dp.x, a0);
                a1 = dot2f(wdhpk[(4 * k8 + 1) * 128 + tid], dp.y, a1);
                a0 = dot2f(wdhpk[(4 * k8 + 2) * 128 + tid], dp.z, a0);
                a1 = dot2f(wdhpk[(4 * k8 + 3) * 128 + tid], dp.w, a1);
            }
            gh_all[(size_t)p * NH + tid] = __float2half(__expf(-fmaxf(a0 + a1, 0.f)));
        } else if (tid < 192) {
            int f = tid - 128;
            float a0 = sbwc[f], a1 = 0.f;
            #pragma unroll
            for (int k8 = 0; k8 < 8; k8++) {
                uint4 gp = *(const uint4*)&gxpk[4 * k8];
                a0 = dot2f(wwcpk[(4 * k8 + 0) * 64 + f], gp.x, a0);
                a1 = dot2f(wwcpk[(4 * k8 + 1) * 64 + f], gp.y, a1);
                a0 = dot2f(wwcpk[(4 * k8 + 2) * 64 + f], gp.z, a0);
                a1 = dot2f(wwcpk[(4 * k8 + 3) * 64 + f], gp.w, a1);
            }
            #pragma unroll
            for (int k8 = 0; k8 < 8; k8++) {
                uint4 mp = *(const uint4*)&mpk2[4 * k8];
                a0 = dot2f(wwcpk[(32 + 4 * k8 + 0) * 64 + f], mp.x, a0);
                a1 = dot2f(wwcpk[(32 + 4 * k8 + 1) * 64 + f], mp.y, a1);
                a0 = dot2f(wwcpk[(32 + 4 * k8 + 2) * 64 + f], mp.z, a0);
                a1 = dot2f(wwcpk[(32 + 4 * k8 + 3) * 64 + f], mp.w, a1);
            }
            al_all[(size_t)p * NF + f] = __float2half(a0 + a1);
        }
        __syncthreads();
    }
}

// ---------------------------------------------------------------------------
// main_kernel: one block per batch element, 512 threads (8 waves).
// Changes vs prior round:
//  - weights anchored in VGPRs via "+v" asm (compiler was rematerializing
//    them from global every step: VGPR_Count=120 < 136 needed)
//  - gate quarter-combine via DPP quad_perm (no ds_swizzle round trips)
//  - x_c / c_c / h handoffs via ds_write_b16 (no pack-shuffles)
//  - 4-step batched input prefetch (x, m, alpha, gamma_h, invms) so the
//    vmcnt(0) drain at __syncthreads exposes HBM latency 1 in 4 steps
//  - 4-step batched imp stores
// ---------------------------------------------------------------------------
__global__ __launch_bounds__(512, 2) void main_kernel(
    const float* __restrict__ values, const float* __restrict__ masks,
    const float* __restrict__ labels, const float* __restrict__ is_train,
    const float* __restrict__ b_hr, const float* __restrict__ b_fr,
    const float* __restrict__ b_ih, const float* __restrict__ b_hh,
    const float* __restrict__ W_out, const float* __restrict__ b_out,
    const uint4* __restrict__ whh_ws, const uint4* __restrict__ wih_ws,
    const uint4* __restrict__ whr_ws, const uint4* __restrict__ wfr_ws,
    const float* __restrict__ invms, const float* __restrict__ inv_istr,
    const __half* __restrict__ gh_all, const __half* __restrict__ al_all,
    float* __restrict__ d_out) {
    __shared__ uint4 wfr4[8 * 64];                 // 8 KB, [k4][f]
    __shared__ float sbhr[64], sbfr[64];
    __shared__ __align__(16) __half hph[128];      // h (pre-decayed), f16
    __shared__ float xp[512];                      // x_h k-partials [kg][f]
    __shared__ float xbuf4[4][64], albuf4[4][64], mbuf4[4][64];
    __shared__ __align__(16) unsigned mpk4[4][32];
    __shared__ __align__(16) __half xcph[64], ccph[64];
    __shared__ __align__(16) unsigned ghpk4[4][64];
    __shared__ float invt4[4];
    __shared__ float hfin[128];

    const int tid = threadIdx.x;
    const int b = blockIdx.x;
    const int s = tid & 3;          // k-quarter within quad
    const int cq = tid >> 2;        // LSTM cell 0..127
    const int kg = tid >> 6;        // wave id (x_h k-group)
    const int fl = tid & 63;        // lane within wave

    // ---- persistent register weights ----
    uint4 whh_q[16];    // h-half:  4 gates x 4 chunks (cols 32s..32s+31)
    uint4 wihc_q[8];    // c_c-half: 4 gates x 2 chunks (cols 16s..16s+15)
    uint4 wihm_q[8];    // m-half:   4 gates x 2 chunks (cols 64+16s..)
    float bg4[4];
    #pragma unroll
    for (int g = 0; g < 4; g++) {
        int r = g * 128 + cq;
        #pragma unroll
        for (int j = 0; j < 4; j++) whh_q[g * 4 + j] = whh_ws[(4 * s + j) * 512 + r];
        #pragma unroll
        for (int j = 0; j < 2; j++) {
            wihc_q[g * 2 + j] = wih_ws[(2 * s + j) * 512 + r];
            wihm_q[g * 2 + j] = wih_ws[(8 + 2 * s + j) * 512 + r];
        }
        bg4[g] = b_ih[r] + b_hh[r];
    }
    uint4 whr_pa = whr_ws[(2 * kg) * 64 + fl];
    uint4 whr_pb = whr_ws[(2 * kg + 1) * 64 + fl];
    wfr4[tid] = wfr_ws[tid];
    if (tid < 64) { sbhr[tid] = b_hr[tid]; sbfr[tid] = b_fr[tid]; }
    if (tid < 128) hph[tid] = __float2half(0.f);

    const float* vp = values + (size_t)b * NT * NF;
    const float* mp = masks + (size_t)b * NT * NF;
    const __half* alp = al_all + (size_t)b * NT * NF;
    const unsigned* ghu = (const unsigned*)(gh_all + (size_t)b * NT * NH);
    float* imp = d_out + 257 + (size_t)b * NT * NF;

    float creg = 0.f;               // c state, replicated across each quad
    float lloss = 0.f;
    float hacc4[4] = {0.f, 0.f, 0.f, 0.f};
    float macc4[4] = {0.f, 0.f, 0.f, 0.f};
    float ccb0 = 0.f, ccb1 = 0.f, ccb2 = 0.f, ccb3 = 0.f;

    // ---- 4-step input batch registers ----
    float xr4[4] = {0.f, 0.f, 0.f, 0.f};
    __half ar4[4] = {};
    float ir4[4] = {0.f, 0.f, 0.f, 0.f};
    float2 mr4[4] = {};
    unsigned gr4[4] = {0u, 0u, 0u, 0u};

    // preamble: load batch for t=0..3
    if (tid >= 256 && tid < 320) {
        int q = tid - 256;
        #pragma unroll
        for (int u = 0; u < 4; u++) {
            xr4[u] = vp[u * NF + q];
            ar4[u] = alp[u * NF + q];
        }
        if (q == 0) {
            #pragma unroll
            for (int u = 0; u < 4; u++) ir4[u] = invms[u];
        }
    } else if (tid >= 320 && tid < 352) {
        int q = tid - 320;
        #pragma unroll
        for (int u = 0; u < 4; u++) mr4[u] = ((const float2*)(mp + u * NF))[q];
    } else if (tid >= 352 && tid < 416) {
        int q = tid - 352;
        #pragma unroll
        for (int u = 0; u < 4; u++) gr4[u] = ghu[(size_t)(u + 1) * 64 + q];
    }
    __syncthreads();

    for (int tb = 0; tb < NT; tb += 4) {
        // anchor the weights in VGPRs (defeats rematerialization/reload)
        #pragma unroll
        for (int i = 0; i < 16; i++) { KEEP4(whh_q[i]); }
        #pragma unroll
        for (int i = 0; i < 8; i++) { KEEP4(wihc_q[i]); KEEP4(wihm_q[i]); }
        KEEP4(whr_pa); KEEP4(whr_pb);

        #pragma unroll
        for (int j = 0; j < 4; j++) {
            const int t = tb + j;
            // ===== P1: (j==0) commit batch + issue next; gate h-dots; x_h =====
            if (j == 0) {
                if (tid >= 256 && tid < 320) {
                    int q = tid - 256;
                    #pragma unroll
                    for (int u = 0; u < 4; u++) {
                        xbuf4[u][q] = xr4[u];
                        albuf4[u][q] = __half2float(ar4[u]);
                    }
                    if (q == 0) {
                        #pragma unroll
                        for (int u = 0; u < 4; u++) invt4[u] = ir4[u];
                    }
                    #pragma unroll
                    for (int u = 0; u < 4; u++) {
                        int tn = tb + 4 + u; if (tn > NT - 1) tn = NT - 1;
                        xr4[u] = vp[tn * NF + q];
                        ar4[u] = alp[tn * NF + q];
                    }
                    if (q == 0) {
                        #pragma unroll
                        for (int u = 0; u < 4; u++) {
                            int tn = tb + 4 + u; if (tn > NT - 1) tn = NT - 1;
                            ir4[u] = invms[tn];
                        }
                    }
                } else if (tid >= 320 && tid < 352) {
                    int q = tid - 320;
                    #pragma unroll
                    for (int u = 0; u < 4; u++) {
                        mbuf4[u][2 * q] = mr4[u].x; mbuf4[u][2 * q + 1] = mr4[u].y;
                        mpk4[u][q] = pack2(mr4[u].x, mr4[u].y);
                    }
                    #pragma unroll
                    for (int u = 0; u < 4; u++) {
                        int tn = tb + 4 + u; if (tn > NT - 1) tn = NT - 1;
                        mr4[u] = ((const float2*)(mp + tn * NF))[q];
                    }
                } else if (tid >= 352 && tid < 416) {
                    int q = tid - 352;
                    #pragma unroll
                    for (int u = 0; u < 4; u++) ghpk4[u][q] = gr4[u];
                    #pragma unroll
                    for (int u = 0; u < 4; u++) {
                        int tg = tb + 5 + u; if (tg > NT - 1) tg = NT - 1;
                        gr4[u] = ghu[(size_t)tg * 64 + q];
                    }
                }
            }
            // h @ W_hh.T partials (4 gates, k-quarter s)
            #pragma unroll
            for (int g = 0; g < 4; g++) {
                float u0 = 0.f, u1 = 0.f;
                #pragma unroll
                for (int jj = 0; jj < 4; jj++) {
                    uint4 hq = *(const uint4*)&hph[32 * s + 8 * jj];
                    uint4 w = whh_q[g * 4 + jj];
                    u0 = dot2f(w.x, hq.x, u0); u1 = dot2f(w.y, hq.y, u1);
                    u0 = dot2f(w.z, hq.z, u0); u1 = dot2f(w.w, hq.w, u1);
                }
                hacc4[g] = u0 + u1;
            }
            // x_h partial: output fl, k in [16*kg, 16*kg+16)
            {
                uint4 hpa = *(const uint4*)&hph[16 * kg];
                uint4 hpb = *(const uint4*)&hph[16 * kg + 8];
                float p0, p1;
                p0 = dot2f(whr_pa.x, hpa.x, 0.f); p1 = dot2f(whr_pa.y, hpa.y, 0.f);
                p0 = dot2f(whr_pa.z, hpa.z, p0);  p1 = dot2f(whr_pa.w, hpa.w, p1);
                p0 = dot2f(whr_pb.x, hpb.x, p0);  p1 = dot2f(whr_pb.y, hpb.y, p1);
                p0 = dot2f(whr_pb.z, hpb.z, p0);  p1 = dot2f(whr_pb.w, hpb.w, p1);
                xp[tid] = p0 + p1;
            }
            __syncthreads();                       // ---- Bar A

            // ===== P2: wave 0 serial imputation chain; waves 1-7 m-dots =====
            if (tid < 64) {
                __builtin_amdgcn_s_setprio(1);
                float xh = sbhr[fl];
                #pragma unroll
                for (int g8 = 0; g8 < 8; g8++) xh += xp[g8 * 64 + fl];
                float xv = xbuf4[j][fl], mv = mbuf4[j][fl];
                float av = albuf4[j][fl], it = invt4[j];
                float xc = mv * xv + (1.f - mv) * xh;
                xcph[fl] = __float2half(xc);
                float b0 = sbfr[fl], b1 = 0.f;
                #pragma unroll
                for (int k4 = 0; k4 < 8; k4++) {
                    uint4 w = wfr4[k4 * 64 + fl];
                    uint4 xq = *(const uint4*)&xcph[8 * k4];
                    b0 = dot2f(w.x, xq.x, b0); b1 = dot2f(w.y, xq.y, b1);
                    b0 = dot2f(w.z, xq.z, b0); b1 = dot2f(w.w, xq.w, b1);
                }
                float zh = b0 + b1;
                float ch = av * zh + (1.f - av) * xh;
                float cc = mv * xv + (1.f - mv) * ch;
                if (j == 0) ccb0 = cc; else if (j == 1) ccb1 = cc;
                else if (j == 2) ccb2 = cc; else ccb3 = cc;
                lloss += (fabsf(xv - xh) + fabsf(xv - zh) + fabsf(xv - ch)) * mv * it;
                ccph[fl] = __float2half(cc);
                if (j == 3) {                      // batched imp stores
                    imp[(tb + 0) * NF + fl] = ccb0;
                    imp[(tb + 1) * NF + fl] = ccb1;
                    imp[(tb + 2) * NF + fl] = ccb2;
                    imp[(tb + 3) * NF + fl] = ccb3;
                }
                __builtin_amdgcn_s_setprio(0);
            } else {
                uint4 mq0 = *(const uint4*)&mpk4[j][8 * s];
                uint4 mq1 = *(const uint4*)&mpk4[j][8 * s + 4];
                #pragma unroll
                for (int g = 0; g < 4; g++) {
                    uint4 wa = wihm_q[g * 2], wb = wihm_q[g * 2 + 1];
                    float u0 = dot2f(wa.x, mq0.x, 0.f), u1 = dot2f(wa.y, mq0.y, 0.f);
                    u0 = dot2f(wa.z, mq0.z, u0); u1 = dot2f(wa.w, mq0.w, u1);
                    u0 = dot2f(wb.x, mq1.x, u0); u1 = dot2f(wb.y, mq1.y, u1);
                    u0 = dot2f(wb.z, mq1.z, u0); u1 = dot2f(wb.w, mq1.w, u1);
                    macc4[g] = u0 + u1;
                }
            }
            __syncthreads();                       // ---- Bar B

            // ===== P3: c_c dots, DPP quad reduce, LSTM pointwise =====
            {
                if (tid < 64) {                    // wave 0's deferred m-dots
                    uint4 mq0 = *(const uint4*)&mpk4[j][8 * s];
                    uint4 mq1 = *(const uint4*)&mpk4[j][8 * s + 4];
                    #pragma unroll
                    for (int g = 0; g < 4; g++) {
                        uint4 wa = wihm_q[g * 2], wb = wihm_q[g * 2 + 1];
                        float u0 = dot2f(wa.x, mq0.x, 0.f), u1 = dot2f(wa.y, mq0.y, 0.f);
                        u0 = dot2f(wa.z, mq0.z, u0); u1 = dot2f(wa.w, mq0.w, u1);
                        u0 = dot2f(wb.x, mq1.x, u0); u1 = dot2f(wb.y, mq1.y, u1);
                        u0 = dot2f(wb.z, mq1.z, u0); u1 = dot2f(wb.w, mq1.w, u1);
                        macc4[g] = u0 + u1;
                    }
                }
                uint4 cq0 = *(const uint4*)&ccph[16 * s];
                uint4 cq1 = *(const uint4*)&ccph[16 * s + 8];
                float gate[4];
                #pragma unroll
                for (int g = 0; g < 4; g++) {
                    uint4 wa = wihc_q[g * 2], wb = wihc_q[g * 2 + 1];
                    float u0 = dot2f(wa.x, cq0.x, 0.f), u1 = dot2f(wa.y, cq0.y, 0.f);
                    u0 = dot2f(wa.z, cq0.z, u0); u1 = dot2f(wa.w, cq0.w, u1);
                    u0 = dot2f(wb.x, cq1.x, u0); u1 = dot2f(wb.y, cq1.y, u1);
                    u0 = dot2f(wb.z, cq1.z, u0); u1 = dot2f(wb.w, cq1.w, u1);
                    float v = hacc4[g] + macc4[g] + (u0 + u1);
                    v = quad_add_x1(v);            // combine k-quarters (DPP)
                    v = quad_add_x2(v);
                    gate[g] = v + bg4[g];
                }
                // pointwise update, replicated across the 4 lanes of the quad
                float cn = sigm(gate[1]) * creg + sigm(gate[0]) * tanh_fast(gate[2]);
                creg = cn;
                float hn = sigm(gate[3]) * tanh_fast(cn);
                float gm = __half2float(((const __half*)&ghpk4[j][0])[cq]);
                float hd = hn * gm;                // pre-decayed h for step t+1
                if (s == 0) hph[cq] = __float2half(hd);
                if (t == NT - 1 && s == 0) hfin[cq] = hn;
            }
            __syncthreads();                       // ---- Bar C (loop top)
        }
    }

    // ---- finale: y_h, prediction, loss contribution ----
    if (tid < 64) {
        float ll = lloss;
        float yp = hfin[tid] * W_out[tid] + hfin[64 + tid] * W_out[64 + tid];
        #pragma unroll
        for (int off = 32; off > 0; off >>= 1) {
            ll += __shfl_down(ll, off);
            yp += __shfl_down(yp, off);
        }
        if (tid == 0) {
            float yh = yp + b_out[0];
            d_out[1 + b] = 1.f / (1.f + expf(-yh));
            float lab = labels[b], istr = is_train[b];
            float maxv = fmaxf(-yh, 0.f);
            float yl = yh - yh * lab + maxv + logf(expf(-maxv) + expf(-yh - maxv));
            atomicAdd(d_out, ll * (1.f / (float)NT) + 0.3f * yl * istr * (*inv_istr));
        }
    }
}

// ---------------------------------------------------------------------------
extern "C" void kernel_launch(void* const* d_in, const int* in_sizes, int n_in,
                              void* d_out, int out_size, void* d_ws, size_t ws_size,
                              hipStream_t stream) {
    const float* values = (const float*)d_in[0];
    const float* masks = (const float*)d_in[1];
    const float* deltas = (const float*)d_in[2];
    const float* labels = (const float*)d_in[3];
    const float* is_train = (const float*)d_in[4];
    const float* W_dh = (const float*)d_in[5];
    const float* b_dh = (const float*)d_in[6];
    const float* W_dx = (const float*)d_in[7];
    const float* b_dx = (const float*)d_in[8];
    const float* W_hr = (const float*)d_in[9];
    const float* b_hr = (const float*)d_in[10];
    const float* W_fr = (const float*)d_in[11];
    const float* b_fr = (const float*)d_in[12];
    const float* W_wc = (const float*)d_in[13];
    const float* b_wc = (const float*)d_in[14];
    const float* W_ih = (const float*)d_in[15];
    const float* b_ih = (const float*)d_in[16];
    const float* W_hh = (const float*)d_in[17];
    const float* b_hh = (const float*)d_in[18];
    const float* W_out = (const float*)d_in[19];
    const float* b_out = (const float*)d_in[20];

    char* ws = (char*)d_ws;
    unsigned* wsu = (unsigned*)d_ws;
    const uint4* whh_ws = (const uint4*)(ws + WHH_OFF);
    const uint4* wih_ws = (const uint4*)(ws + WIH_OFF);
    const uint4* whr_ws = (const uint4*)(ws + WHR_OFF);
    const uint4* wfr_ws = (const uint4*)(ws + WFR_OFF);
    float* invms = (float*)(ws + INVMS_OFF);
    float* inv_istr = (float*)(ws + ISTR_OFF);
    __half* gh_all = (__half*)(ws + GH_OFF);
    __half* al_all = (__half*)(ws + AL_OFF);
    float* out_f = (float*)d_out;

    prep_w<<<280, 256, 0, stream>>>(W_hh, W_ih, W_hr, W_fr, wsu);
    prep_msum<<<513, 256, 0, stream>>>(masks, is_train, invms, inv_istr, out_f);
    ga_kernel<<<4096, 256, 0, stream>>>(deltas, masks, W_dh, b_dh, W_dx, b_dx,
                                        W_wc, b_wc, gh_all, al_all);
    main_kernel<<<NBATCH, 512, 0, stream>>>(values, masks, labels, is_train,
                                            b_hr, b_fr, b_ih, b_hh, W_out, b_out,
                                            whh_ws, wih_ws, whr_ws, wfr_ws,
                                            invms, inv_istr, gh_all, al_all, out_f);
}

// Round 4
// 1240.231 us; speedup vs baseline: 1.1967x; 1.0393x over previous
//
#include <hip/hip_runtime.h>
#include <hip/hip_fp16.h>

// Problem: B=256, T=512, F=64, H=128  (GRU-D / BRITS-style recurrence)
// d_in: 0 values,1 masks,2 deltas,3 labels,4 is_train,5 W_dh,6 b_dh,7 W_dx,8 b_dx,
//       9 W_hr,10 b_hr,11 W_fr,12 b_fr,13 W_wc,14 b_wc,15 W_ih,16 b_ih,17 W_hh,
//       18 b_hh,19 W_out,20 b_out
// d_out (fp32): [0]=loss, [1..256]=predictions, [257..]=imputations [B,T,F]

#define NBATCH 256
#define NT 512
#define NF 64
#define NH 128

// ---- workspace byte offsets (all 16B aligned) ----
#define WHH_OFF   0u           // [16][512] uint4 packed f16 rows of W_hh
#define WIH_OFF   131072u      // [16][512] uint4 packed f16 rows of W_ih
#define WHR_OFF   262144u      // [16][64]  uint4 packed f16 rows of W_hr
#define WFR_OFF   278528u      // [8][64]   uint4 packed f16 rows of W_fr (diag zeroed)
#define INVMS_OFF 286720u      // f32[512]
#define ISTR_OFF  288768u      // f32[1]
#define GH_OFF    294912u      // f16 [B*T*128] gamma_h
#define AL_OFF    33849344u    // f16 [B*T*64]  alpha
// total ws needed ~50.7 MB

typedef _Float16 half2_t __attribute__((ext_vector_type(2)));

__device__ __forceinline__ unsigned pack2(float a, float b) {
    __half2 h = __floats2half2_rn(a, b);
    return __builtin_bit_cast(unsigned, h);
}

__device__ __forceinline__ float dot2f(unsigned w, unsigned a, float acc) {
#if __has_builtin(__builtin_amdgcn_fdot2)
    return __builtin_amdgcn_fdot2(__builtin_bit_cast(half2_t, w),
                                  __builtin_bit_cast(half2_t, a), acc, false);
#else
    float2 wf = __half22float2(__builtin_bit_cast(__half2, w));
    float2 af = __half22float2(__builtin_bit_cast(__half2, a));
    return acc + wf.x * af.x + wf.y * af.y;
#endif
}

__device__ __forceinline__ float sigm(float x) { return 1.f / (1.f + __expf(-x)); }
__device__ __forceinline__ float tanh_fast(float x) { return 1.f - 2.f / (__expf(2.f * x) + 1.f); }

// Intra-quad butterfly adds via DPP quad_perm (register-only, ~4cy vs ~120cy
// for ds_swizzle-based __shfl_xor).
__device__ __forceinline__ float quad_add_x1(float v) {
    int r = __builtin_amdgcn_update_dpp(0, __builtin_bit_cast(int, v),
                                        0xB1 /*[1,0,3,2]*/, 0xF, 0xF, true);
    return v + __builtin_bit_cast(float, r);
}
__device__ __forceinline__ float quad_add_x2(float v) {
    int r = __builtin_amdgcn_update_dpp(0, __builtin_bit_cast(int, v),
                                        0x4E /*[2,3,0,1]*/, 0xF, 0xF, true);
    return v + __builtin_bit_cast(float, r);
}

// Keep-alive anchor: forces the value to live in a VGPR and makes it opaque,
// so the compiler cannot rematerialize it by re-loading from global memory.
#define KEEP4(u) asm volatile("" : "+v"(u.x), "+v"(u.y), "+v"(u.z), "+v"(u.w))

// ---------------------------------------------------------------------------
// prep_w: pack W_hh / W_ih / W_hr / W_fr(zero-diag) rows into f16x2 uint4 layout
// ---------------------------------------------------------------------------
__global__ __launch_bounds__(256) void prep_w(const float* __restrict__ Whh,
                                              const float* __restrict__ Wih,
                                              const float* __restrict__ Whr,
                                              const float* __restrict__ Wfr,
                                              unsigned* __restrict__ wsu) {
    int o = blockIdx.x * 256 + threadIdx.x;
    float v0, v1;
    if (o < 32768) {                      // W_hh [512][128]
        int c = o & 3, r = (o >> 2) & 511, cb = o >> 11;
        int col = 8 * cb + 2 * c;
        v0 = Whh[r * 128 + col]; v1 = Whh[r * 128 + col + 1];
    } else if (o < 65536) {               // W_ih [512][128]
        int o2 = o - 32768;
        int c = o2 & 3, r = (o2 >> 2) & 511, cb = o2 >> 11;
        int col = 8 * cb + 2 * c;
        v0 = Wih[r * 128 + col]; v1 = Wih[r * 128 + col + 1];
    } else if (o < 69632) {               // W_hr [64][128]
        int o3 = o - 65536;
        int c = o3 & 3, f = (o3 >> 2) & 63, cb = o3 >> 8;
        int col = 8 * cb + 2 * c;
        v0 = Whr[f * 128 + col]; v1 = Whr[f * 128 + col + 1];
    } else if (o < 71680) {               // W_fr [64][64], zero diagonal
        int o4 = o - 69632;
        int c = o4 & 3, f = (o4 >> 2) & 63, cb = o4 >> 8;
        int col = 8 * cb + 2 * c;
        v0 = (col == f) ? 0.f : Wfr[f * 64 + col];
        v1 = (col + 1 == f) ? 0.f : Wfr[f * 64 + col + 1];
    } else {
        return;
    }
    wsu[o] = pack2(v0, v1);
}

// ---------------------------------------------------------------------------
// prep_msum: invms[t] = 1/(sum_b,f masks[b,t,f] + 1e-5); block 512 does
// inv_istr = 1/(sum is_train + 1e-5) and zeroes d_out[0].
// ---------------------------------------------------------------------------
__global__ __launch_bounds__(256) void prep_msum(const float* __restrict__ masks,
                                                 const float* __restrict__ is_train,
                                                 float* __restrict__ invms,
                                                 float* __restrict__ inv_istr,
                                                 float* __restrict__ d_out0) {
    __shared__ float red[256];
    int tid = threadIdx.x;
    int t = blockIdx.x;
    if (t < NT) {
        int f = tid & 63, br = tid >> 6;
        float s = 0.f;
        for (int i = 0; i < 64; i++) {
            int b = br + i * 4;
            s += masks[((size_t)b * NT + t) * NF + f];
        }
        red[tid] = s;
        __syncthreads();
        for (int off = 128; off > 0; off >>= 1) {
            if (tid < off) red[tid] += red[tid + off];
            __syncthreads();
        }
        if (tid == 0) invms[t] = 1.f / (red[0] + 1e-5f);
    } else {
        red[tid] = is_train[tid];
        __syncthreads();
        for (int off = 128; off > 0; off >>= 1) {
            if (tid < off) red[tid] += red[tid + off];
            __syncthreads();
        }
        if (tid == 0) {
            *inv_istr = 1.f / (red[0] + 1e-5f);
            *d_out0 = 0.f;
        }
    }
}

// ---------------------------------------------------------------------------
// ga_kernel: precompute gamma_h[b,t,128] and alpha[b,t,64] (f16), both pure
// input functions. One (b,t) pair per inner iteration, 32 per block.
// ---------------------------------------------------------------------------
__global__ __launch_bounds__(256) void ga_kernel(const float* __restrict__ deltas,
                                                 const float* __restrict__ masks,
                                                 const float* __restrict__ Wdh,
                                                 const float* __restrict__ bdh,
                                                 const float* __restrict__ Wdx,
                                                 const float* __restrict__ bdx,
                                                 const float* __restrict__ Wwc,
                                                 const float* __restrict__ bwc,
                                                 __half* __restrict__ gh_all,
                                                 __half* __restrict__ al_all) {
    __shared__ unsigned wdhpk[32 * 128];   // [k2][j]  f16x2 of W_dh cols (2k2,2k2+1)
    __shared__ unsigned wwcpk[64 * 64];    // [k2][f]
    __shared__ float sbdh[128], sbdx[64], swdx[64], sbwc[64];
    __shared__ float dbuf[64];
    __shared__ __align__(16) unsigned dpk[32], gxpk[32], mpk2[32];
    int tid = threadIdx.x;

    for (int o = tid; o < 4096; o += 256) {    // W_dh [128][64] -> [k2][j]
        int j = o & 127, k2 = o >> 7;
        wdhpk[o] = pack2(Wdh[j * 64 + 2 * k2], Wdh[j * 64 + 2 * k2 + 1]);
    }
    for (int o = tid; o < 4096; o += 256) {    // W_wc [64][128] -> [k2][f]
        int f = o & 63, k2 = o >> 6;
        wwcpk[o] = pack2(Wwc[f * 128 + 2 * k2], Wwc[f * 128 + 2 * k2 + 1]);
    }
    if (tid < 128) sbdh[tid] = bdh[tid];
    if (tid < 64) {
        sbdx[tid] = bdx[tid];
        swdx[tid] = Wdx[tid * 65];             // diagonal of W_dx
        sbwc[tid] = bwc[tid];
    }
    __syncthreads();

    for (int i = 0; i < 32; i++) {
        int p = blockIdx.x * 32 + i;           // p = b*T + t
        if (tid < 32) {
            float2 dv = ((const float2*)(deltas + (size_t)p * NF))[tid];
            dbuf[2 * tid] = dv.x; dbuf[2 * tid + 1] = dv.y;
            dpk[tid] = pack2(dv.x, dv.y);
        } else if (tid < 64) {
            int q = tid - 32;
            float2 mv = ((const float2*)(masks + (size_t)p * NF))[q];
            mpk2[q] = pack2(mv.x, mv.y);
        }
        __syncthreads();
        if (tid < 64) {
            float gx = __expf(-fmaxf(dbuf[tid] * swdx[tid] + sbdx[tid], 0.f));
            float oth = __shfl_xor(gx, 1);
            if (!(tid & 1)) gxpk[tid >> 1] = pack2(gx, oth);
        }
        __syncthreads();
        if (tid < 128) {
            float a0 = sbdh[tid], a1 = 0.f;
            #pragma unroll
            for (int k8 = 0; k8 < 8; k8++) {
                uint4 dp = *(const uint4*)&dpk[4 * k8];
                a0 = dot2f(wdhpk[(4 * k8 + 0) * 128 + tid], dp.x, a0);
                a1 = dot2f(wdhpk[(4 * k8 + 1) * 128 + tid], dp.y, a1);
                a0 = dot2f(wdhpk[(4 * k8 + 2) * 128 + tid], dp.z, a0);
                a1 = dot2f(wdhpk[(4 * k8 + 3) * 128 + tid], dp.w, a1);
            }
            gh_all[(size_t)p * NH + tid] = __float2half(__expf(-fmaxf(a0 + a1, 0.f)));
        } else if (tid < 192) {
            int f = tid - 128;
            float a0 = sbwc[f], a1 = 0.f;
            #pragma unroll
            for (int k8 = 0; k8 < 8; k8++) {
                uint4 gp = *(const uint4*)&gxpk[4 * k8];
                a0 = dot2f(wwcpk[(4 * k8 + 0) * 64 + f], gp.x, a0);
                a1 = dot2f(wwcpk[(4 * k8 + 1) * 64 + f], gp.y, a1);
                a0 = dot2f(wwcpk[(4 * k8 + 2) * 64 + f], gp.z, a0);
                a1 = dot2f(wwcpk[(4 * k8 + 3) * 64 + f], gp.w, a1);
            }
            #pragma unroll
            for (int k8 = 0; k8 < 8; k8++) {
                uint4 mp = *(const uint4*)&mpk2[4 * k8];
                a0 = dot2f(wwcpk[(32 + 4 * k8 + 0) * 64 + f], mp.x, a0);
                a1 = dot2f(wwcpk[(32 + 4 * k8 + 1) * 64 + f], mp.y, a1);
                a0 = dot2f(wwcpk[(32 + 4 * k8 + 2) * 64 + f], mp.z, a0);
                a1 = dot2f(wwcpk[(32 + 4 * k8 + 3) * 64 + f], mp.w, a1);
            }
            al_all[(size_t)p * NF + f] = __float2half(a0 + a1);
        }
        __syncthreads();
    }
}

// ---------------------------------------------------------------------------
// main_kernel: one block per batch element, 512 threads (8 waves).
// Grid = 1 block/CU -> LDS (160KB) and VGPRs (256 @ 2 waves/SIMD) are free.
// Changes vs prior round:
//  - __launch_bounds__(512, 1): unlock 256-VGPR budget (allocator was capping
//    at 128 < the 136 regs of weights, spilling to scratch: WRITE_SIZE +3MB)
//  - m-half of W_ih moved to LDS ([512][9]-padded uint4, ~2-way conflicts max)
//    -> register weight footprint 104 (whh 64 + wihc 32 + whr 8): fits.
// ---------------------------------------------------------------------------
__global__ __launch_bounds__(512, 1) void main_kernel(
    const float* __restrict__ values, const float* __restrict__ masks,
    const float* __restrict__ labels, const float* __restrict__ is_train,
    const float* __restrict__ b_hr, const float* __restrict__ b_fr,
    const float* __restrict__ b_ih, const float* __restrict__ b_hh,
    const float* __restrict__ W_out, const float* __restrict__ b_out,
    const uint4* __restrict__ whh_ws, const uint4* __restrict__ wih_ws,
    const uint4* __restrict__ whr_ws, const uint4* __restrict__ wfr_ws,
    const float* __restrict__ invms, const float* __restrict__ inv_istr,
    const __half* __restrict__ gh_all, const __half* __restrict__ al_all,
    float* __restrict__ d_out) {
    __shared__ uint4 wm[512 * 9];                  // 73.7 KB: W_ih m-half, [row][chunk(+pad)]
    __shared__ uint4 wfr4[8 * 64];                 // 8 KB, [k4][f]
    __shared__ float sbhr[64], sbfr[64];
    __shared__ __align__(16) __half hph[128];      // h (pre-decayed), f16
    __shared__ float xp[512];                      // x_h k-partials [kg][f]
    __shared__ float xbuf4[4][64], albuf4[4][64], mbuf4[4][64];
    __shared__ __align__(16) unsigned mpk4[4][32];
    __shared__ __align__(16) __half xcph[64], ccph[64];
    __shared__ __align__(16) unsigned ghpk4[4][64];
    __shared__ float invt4[4];
    __shared__ float hfin[128];

    const int tid = threadIdx.x;
    const int b = blockIdx.x;
    const int s = tid & 3;          // k-quarter within quad
    const int cq = tid >> 2;        // LSTM cell 0..127
    const int kg = tid >> 6;        // wave id (x_h k-group)
    const int fl = tid & 63;        // lane within wave

    // ---- persistent register weights (104 VGPRs) ----
    uint4 whh_q[16];    // h-half:  4 gates x 4 chunks (cols 32s..32s+31)
    uint4 wihc_q[8];    // c_c-half: 4 gates x 2 chunks (cols 16s..16s+15)
    float bg4[4];
    #pragma unroll
    for (int g = 0; g < 4; g++) {
        int r = g * 128 + cq;
        #pragma unroll
        for (int j = 0; j < 4; j++) whh_q[g * 4 + j] = whh_ws[(4 * s + j) * 512 + r];
        #pragma unroll
        for (int j = 0; j < 2; j++)
            wihc_q[g * 2 + j] = wih_ws[(2 * s + j) * 512 + r];
        bg4[g] = b_ih[r] + b_hh[r];
    }
    uint4 whr_pa = whr_ws[(2 * kg) * 64 + fl];
    uint4 whr_pb = whr_ws[(2 * kg + 1) * 64 + fl];
    // W_ih m-half -> LDS, [row][chunk] with row stride 9 (pad kills conflicts)
    for (int o = tid; o < 4096; o += 512) {
        int r = o & 511, c = o >> 9;
        wm[r * 9 + c] = wih_ws[(8 + c) * 512 + r];
    }
    wfr4[tid] = wfr_ws[tid];
    if (tid < 64) { sbhr[tid] = b_hr[tid]; sbfr[tid] = b_fr[tid]; }
    if (tid < 128) hph[tid] = __float2half(0.f);

    const float* vp = values + (size_t)b * NT * NF;
    const float* mp = masks + (size_t)b * NT * NF;
    const __half* alp = al_all + (size_t)b * NT * NF;
    const unsigned* ghu = (const unsigned*)(gh_all + (size_t)b * NT * NH);
    float* imp = d_out + 257 + (size_t)b * NT * NF;

    float creg = 0.f;               // c state, replicated across each quad
    float lloss = 0.f;
    float hacc4[4] = {0.f, 0.f, 0.f, 0.f};
    float macc4[4] = {0.f, 0.f, 0.f, 0.f};
    float ccb0 = 0.f, ccb1 = 0.f, ccb2 = 0.f, ccb3 = 0.f;

    // ---- 4-step input batch registers ----
    float xr4[4] = {0.f, 0.f, 0.f, 0.f};
    __half ar4[4] = {};
    float ir4[4] = {0.f, 0.f, 0.f, 0.f};
    float2 mr4[4] = {};
    unsigned gr4[4] = {0u, 0u, 0u, 0u};

    // preamble: load batch for t=0..3
    if (tid >= 256 && tid < 320) {
        int q = tid - 256;
        #pragma unroll
        for (int u = 0; u < 4; u++) {
            xr4[u] = vp[u * NF + q];
            ar4[u] = alp[u * NF + q];
        }
        if (q == 0) {
            #pragma unroll
            for (int u = 0; u < 4; u++) ir4[u] = invms[u];
        }
    } else if (tid >= 320 && tid < 352) {
        int q = tid - 320;
        #pragma unroll
        for (int u = 0; u < 4; u++) mr4[u] = ((const float2*)(mp + u * NF))[q];
    } else if (tid >= 352 && tid < 416) {
        int q = tid - 352;
        #pragma unroll
        for (int u = 0; u < 4; u++) gr4[u] = ghu[(size_t)(u + 1) * 64 + q];
    }
    __syncthreads();

    const int wmr = cq * 9;          // LDS row base for this thread's m-weights

    for (int tb = 0; tb < NT; tb += 4) {
        // anchor the weights in VGPRs (defeats rematerialization/reload)
        #pragma unroll
        for (int i = 0; i < 16; i++) { KEEP4(whh_q[i]); }
        #pragma unroll
        for (int i = 0; i < 8; i++) { KEEP4(wihc_q[i]); }
        KEEP4(whr_pa); KEEP4(whr_pb);

        #pragma unroll
        for (int j = 0; j < 4; j++) {
            const int t = tb + j;
            // ===== P1: (j==0) commit batch + issue next; gate h-dots; x_h =====
            if (j == 0) {
                if (tid >= 256 && tid < 320) {
                    int q = tid - 256;
                    #pragma unroll
                    for (int u = 0; u < 4; u++) {
                        xbuf4[u][q] = xr4[u];
                        albuf4[u][q] = __half2float(ar4[u]);
                    }
                    if (q == 0) {
                        #pragma unroll
                        for (int u = 0; u < 4; u++) invt4[u] = ir4[u];
                    }
                    #pragma unroll
                    for (int u = 0; u < 4; u++) {
                        int tn = tb + 4 + u; if (tn > NT - 1) tn = NT - 1;
                        xr4[u] = vp[tn * NF + q];
                        ar4[u] = alp[tn * NF + q];
                    }
                    if (q == 0) {
                        #pragma unroll
                        for (int u = 0; u < 4; u++) {
                            int tn = tb + 4 + u; if (tn > NT - 1) tn = NT - 1;
                            ir4[u] = invms[tn];
                        }
                    }
                } else if (tid >= 320 && tid < 352) {
                    int q = tid - 320;
                    #pragma unroll
                    for (int u = 0; u < 4; u++) {
                        mbuf4[u][2 * q] = mr4[u].x; mbuf4[u][2 * q + 1] = mr4[u].y;
                        mpk4[u][q] = pack2(mr4[u].x, mr4[u].y);
                    }
                    #pragma unroll
                    for (int u = 0; u < 4; u++) {
                        int tn = tb + 4 + u; if (tn > NT - 1) tn = NT - 1;
                        mr4[u] = ((const float2*)(mp + tn * NF))[q];
                    }
                } else if (tid >= 352 && tid < 416) {
                    int q = tid - 352;
                    #pragma unroll
                    for (int u = 0; u < 4; u++) ghpk4[u][q] = gr4[u];
                    #pragma unroll
                    for (int u = 0; u < 4; u++) {
                        int tg = tb + 5 + u; if (tg > NT - 1) tg = NT - 1;
                        gr4[u] = ghu[(size_t)tg * 64 + q];
                    }
                }
            }
            // h @ W_hh.T partials (4 gates, k-quarter s)
            #pragma unroll
            for (int g = 0; g < 4; g++) {
                float u0 = 0.f, u1 = 0.f;
                #pragma unroll
                for (int jj = 0; jj < 4; jj++) {
                    uint4 hq = *(const uint4*)&hph[32 * s + 8 * jj];
                    uint4 w = whh_q[g * 4 + jj];
                    u0 = dot2f(w.x, hq.x, u0); u1 = dot2f(w.y, hq.y, u1);
                    u0 = dot2f(w.z, hq.z, u0); u1 = dot2f(w.w, hq.w, u1);
                }
                hacc4[g] = u0 + u1;
            }
            // x_h partial: output fl, k in [16*kg, 16*kg+16)
            {
                uint4 hpa = *(const uint4*)&hph[16 * kg];
                uint4 hpb = *(const uint4*)&hph[16 * kg + 8];
                float p0, p1;
                p0 = dot2f(whr_pa.x, hpa.x, 0.f); p1 = dot2f(whr_pa.y, hpa.y, 0.f);
                p0 = dot2f(whr_pa.z, hpa.z, p0);  p1 = dot2f(whr_pa.w, hpa.w, p1);
                p0 = dot2f(whr_pb.x, hpb.x, p0);  p1 = dot2f(whr_pb.y, hpb.y, p1);
                p0 = dot2f(whr_pb.z, hpb.z, p0);  p1 = dot2f(whr_pb.w, hpb.w, p1);
                xp[tid] = p0 + p1;
            }
            __syncthreads();                       // ---- Bar A

            // ===== P2: wave 0 serial imputation chain; waves 1-7 m-dots =====
            if (tid < 64) {
                __builtin_amdgcn_s_setprio(1);
                float xh = sbhr[fl];
                #pragma unroll
                for (int g8 = 0; g8 < 8; g8++) xh += xp[g8 * 64 + fl];
                float xv = xbuf4[j][fl], mv = mbuf4[j][fl];
                float av = albuf4[j][fl], it = invt4[j];
                float xc = mv * xv + (1.f - mv) * xh;
                xcph[fl] = __float2half(xc);
                float b0 = sbfr[fl], b1 = 0.f;
                #pragma unroll
                for (int k4 = 0; k4 < 8; k4++) {
                    uint4 w = wfr4[k4 * 64 + fl];
                    uint4 xq = *(const uint4*)&xcph[8 * k4];
                    b0 = dot2f(w.x, xq.x, b0); b1 = dot2f(w.y, xq.y, b1);
                    b0 = dot2f(w.z, xq.z, b0); b1 = dot2f(w.w, xq.w, b1);
                }
                float zh = b0 + b1;
                float ch = av * zh + (1.f - av) * xh;
                float cc = mv * xv + (1.f - mv) * ch;
                if (j == 0) ccb0 = cc; else if (j == 1) ccb1 = cc;
                else if (j == 2) ccb2 = cc; else ccb3 = cc;
                lloss += (fabsf(xv - xh) + fabsf(xv - zh) + fabsf(xv - ch)) * mv * it;
                ccph[fl] = __float2half(cc);
                if (j == 3) {                      // batched imp stores
                    imp[(tb + 0) * NF + fl] = ccb0;
                    imp[(tb + 1) * NF + fl] = ccb1;
                    imp[(tb + 2) * NF + fl] = ccb2;
                    imp[(tb + 3) * NF + fl] = ccb3;
                }
                __builtin_amdgcn_s_setprio(0);
            } else {
                uint4 mq0 = *(const uint4*)&mpk4[j][8 * s];
                uint4 mq1 = *(const uint4*)&mpk4[j][8 * s + 4];
                #pragma unroll
                for (int g = 0; g < 4; g++) {
                    uint4 wa = wm[(g * 128 + cq) * 9 + 2 * s];
                    uint4 wb = wm[(g * 128 + cq) * 9 + 2 * s + 1];
                    float u0 = dot2f(wa.x, mq0.x, 0.f), u1 = dot2f(wa.y, mq0.y, 0.f);
                    u0 = dot2f(wa.z, mq0.z, u0); u1 = dot2f(wa.w, mq0.w, u1);
                    u0 = dot2f(wb.x, mq1.x, u0); u1 = dot2f(wb.y, mq1.y, u1);
                    u0 = dot2f(wb.z, mq1.z, u0); u1 = dot2f(wb.w, mq1.w, u1);
                    macc4[g] = u0 + u1;
                }
            }
            __syncthreads();                       // ---- Bar B

            // ===== P3: c_c dots, DPP quad reduce, LSTM pointwise =====
            {
                if (tid < 64) {                    // wave 0's deferred m-dots
                    uint4 mq0 = *(const uint4*)&mpk4[j][8 * s];
                    uint4 mq1 = *(const uint4*)&mpk4[j][8 * s + 4];
                    #pragma unroll
                    for (int g = 0; g < 4; g++) {
                        uint4 wa = wm[(g * 128 + cq) * 9 + 2 * s];
                        uint4 wb = wm[(g * 128 + cq) * 9 + 2 * s + 1];
                        float u0 = dot2f(wa.x, mq0.x, 0.f), u1 = dot2f(wa.y, mq0.y, 0.f);
                        u0 = dot2f(wa.z, mq0.z, u0); u1 = dot2f(wa.w, mq0.w, u1);
                        u0 = dot2f(wb.x, mq1.x, u0); u1 = dot2f(wb.y, mq1.y, u1);
                        u0 = dot2f(wb.z, mq1.z, u0); u1 = dot2f(wb.w, mq1.w, u1);
                        macc4[g] = u0 + u1;
                    }
                }
                uint4 cq0 = *(const uint4*)&ccph[16 * s];
                uint4 cq1 = *(const uint4*)&ccph[16 * s + 8];
                float gate[4];
                #pragma unroll
                for (int g = 0; g < 4; g++) {
                    uint4 wa = wihc_q[g * 2], wb = wihc_q[g * 2 + 1];
                    float u0 = dot2f(wa.x, cq0.x, 0.f), u1 = dot2f(wa.y, cq0.y, 0.f);
                    u0 = dot2f(wa.z, cq0.z, u0); u1 = dot2f(wa.w, cq0.w, u1);
                    u0 = dot2f(wb.x, cq1.x, u0); u1 = dot2f(wb.y, cq1.y, u1);
                    u0 = dot2f(wb.z, cq1.z, u0); u1 = dot2f(wb.w, cq1.w, u1);
                    float v = hacc4[g] + macc4[g] + (u0 + u1);
                    v = quad_add_x1(v);            // combine k-quarters (DPP)
                    v = quad_add_x2(v);
                    gate[g] = v + bg4[g];
                }
                // pointwise update, replicated across the 4 lanes of the quad
                float cn = sigm(gate[1]) * creg + sigm(gate[0]) * tanh_fast(gate[2]);
                creg = cn;
                float hn = sigm(gate[3]) * tanh_fast(cn);
                float gm = __half2float(((const __half*)&ghpk4[j][0])[cq]);
                float hd = hn * gm;                // pre-decayed h for step t+1
                if (s == 0) hph[cq] = __float2half(hd);
                if (t == NT - 1 && s == 0) hfin[cq] = hn;
            }
            __syncthreads();                       // ---- Bar C (loop top)
        }
    }

    // ---- finale: y_h, prediction, loss contribution ----
    if (tid < 64) {
        float ll = lloss;
        float yp = hfin[tid] * W_out[tid] + hfin[64 + tid] * W_out[64 + tid];
        #pragma unroll
        for (int off = 32; off > 0; off >>= 1) {
            ll += __shfl_down(ll, off);
            yp += __shfl_down(yp, off);
        }
        if (tid == 0) {
            float yh = yp + b_out[0];
            d_out[1 + b] = 1.f / (1.f + expf(-yh));
            float lab = labels[b], istr = is_train[b];
            float maxv = fmaxf(-yh, 0.f);
            float yl = yh - yh * lab + maxv + logf(expf(-maxv) + expf(-yh - maxv));
            atomicAdd(d_out, ll * (1.f / (float)NT) + 0.3f * yl * istr * (*inv_istr));
        }
    }
}

// ---------------------------------------------------------------------------
extern "C" void kernel_launch(void* const* d_in, const int* in_sizes, int n_in,
                              void* d_out, int out_size, void* d_ws, size_t ws_size,
                              hipStream_t stream) {
    const float* values = (const float*)d_in[0];
    const float* masks = (const float*)d_in[1];
    const float* deltas = (const float*)d_in[2];
    const float* labels = (const float*)d_in[3];
    const float* is_train = (const float*)d_in[4];
    const float* W_dh = (const float*)d_in[5];
    const float* b_dh = (const float*)d_in[6];
    const float* W_dx = (const float*)d_in[7];
    const float* b_dx = (const float*)d_in[8];
    const float* W_hr = (const float*)d_in[9];
    const float* b_hr = (const float*)d_in[10];
    const float* W_fr = (const float*)d_in[11];
    const float* b_fr = (const float*)d_in[12];
    const float* W_wc = (const float*)d_in[13];
    const float* b_wc = (const float*)d_in[14];
    const float* W_ih = (const float*)d_in[15];
    const float* b_ih = (const float*)d_in[16];
    const float* W_hh = (const float*)d_in[17];
    const float* b_hh = (const float*)d_in[18];
    const float* W_out = (const float*)d_in[19];
    const float* b_out = (const float*)d_in[20];

    char* ws = (char*)d_ws;
    unsigned* wsu = (unsigned*)d_ws;
    const uint4* whh_ws = (const uint4*)(ws + WHH_OFF);
    const uint4* wih_ws = (const uint4*)(ws + WIH_OFF);
    const uint4* whr_ws = (const uint4*)(ws + WHR_OFF);
    const uint4* wfr_ws = (const uint4*)(ws + WFR_OFF);
    float* invms = (float*)(ws + INVMS_OFF);
    float* inv_istr = (float*)(ws + ISTR_OFF);
    __half* gh_all = (__half*)(ws + GH_OFF);
    __half* al_all = (__half*)(ws + AL_OFF);
    float* out_f = (float*)d_out;

    prep_w<<<280, 256, 0, stream>>>(W_hh, W_ih, W_hr, W_fr, wsu);
    prep_msum<<<513, 256, 0, stream>>>(masks, is_train, invms, inv_istr, out_f);
    ga_kernel<<<4096, 256, 0, stream>>>(deltas, masks, W_dh, b_dh, W_dx, b_dx,
                                        W_wc, b_wc, gh_all, al_all);
    main_kernel<<<NBATCH, 512, 0, stream>>>(values, masks, labels, is_train,
                                            b_hr, b_fr, b_ih, b_hh, W_out, b_out,
                                            whh_ws, wih_ws, whr_ws, wfr_ws,
                                            invms, inv_istr, gh_all, al_all, out_f);
}